// Round 3
// baseline (609.208 us; speedup 1.0000x reference)
//
#include <hip/hip_runtime.h>
#include <hip/hip_bf16.h>

// VectorQuantiser: x [32,64,64,64] f32, embeddings [64,1024] f32.
// argmin_k ||z - e_k||^2 over K=1024 for N=131072 rows of D=64; out = codewords.
//
//  k0 vq_prep:  E -> ET[k][d] f32; ckseq[k] = sequential f32 sum_d e^2 (numpy
//               axis-0 order, used by BOTH main scores and refine); EB = bf16
//               B-fragments pre-arranged in mfma lane order.
//  k1 vq_mfma:  bf16 MFMA distance GEMM (hi term only) + branchless top-2 +
//               fused gather. Rows with (2nd-best) < MARGIN -> refine list.
//  k2 vq_refine: exact numpy-f32-chain emulation for flagged rows (validated
//               in R2), rewrites those output rows.

#define NROWS (32 * 64 * 64)   // 131072
#define DIM   64
#define KCB   1024
#define MARGIN 0.015f

// ws layout (bytes):
#define ET_OFF    0           // float[1024*64] = 262144
#define CK_OFF    262144      // float[1024] + 16 pad  -> 4352
#define EB_OFF    266496      // bf16 frags: 1024*128 B + 1 tile pad = 133376
#define CNT_OFF   399872      // int (+pad)
#define LIST_OFF  400128      // int[cap]

typedef float  f32x4 __attribute__((ext_vector_type(4)));
typedef short  s16x8 __attribute__((ext_vector_type(8)));

static __device__ inline short bfb(float f) {   // f32 -> bf16 bits, RNE
    union { float f; unsigned u; } c{f};
    unsigned r = c.u + 0x7fffu + ((c.u >> 16) & 1u);
    return (short)(r >> 16);
}

__global__ void vq_prep(const float* __restrict__ E,
                        float* __restrict__ ET,
                        float* __restrict__ ckseq,
                        char* __restrict__ EB) {
    #pragma clang fp contract(off)
    int n = blockIdx.x * blockDim.x + threadIdx.x;  // codebook col 0..1023
    if (n >= KCB) return;
    float col[DIM];
    float c = 0.f;
    #pragma unroll
    for (int d = 0; d < DIM; ++d) {
        float v = E[d * KCB + n];      // coalesced along n
        col[d] = v;
        ET[n * DIM + d] = v;
        float q = v * v;
        c = c + q;                     // sequential (numpy axis-0 reduce)
    }
    ckseq[n] = c;
    // B-fragments: lane l of a wave needs e[s*32 + (l>>4)*8 + j][col], j=0..7
    // contiguous. Record (n,s,g): 8 bf16 = 16 B at EB + n*128 + s*64 + g*16.
    #pragma unroll
    for (int s = 0; s < 2; ++s)
        #pragma unroll
        for (int g = 0; g < 4; ++g) {
            s16x8 w;
            #pragma unroll
            for (int j = 0; j < 8; ++j)
                w[j] = bfb(col[s * 32 + g * 8 + j]);
            *(s16x8*)(EB + n * 128 + s * 64 + g * 16) = w;
        }
}

__global__ __launch_bounds__(256, 2)
void vq_mfma(const float* __restrict__ x, const float* __restrict__ ck,
             const char* __restrict__ EB, const float* __restrict__ ET,
             float* __restrict__ out, int* __restrict__ count,
             int* __restrict__ list, int list_cap) {
    __shared__ int idxbuf[256];

    const int tid  = threadIdx.x;
    const int lane = tid & 63;
    const int wv   = tid >> 6;            // wave 0..3
    const int l15  = lane & 15;
    const int g    = lane >> 4;           // 0..3
    const int rowbase = blockIdx.x * 256; // 256 rows per block

    // ---- A fragments: 4 rowtiles x 2 dsteps, f32 -> bf16 in regs ----
    s16x8 aF[4][2];
    #pragma unroll
    for (int rt = 0; rt < 4; ++rt) {
        int row = rowbase + wv * 64 + rt * 16 + l15;
        const float* xp = x + (size_t)row * DIM + g * 8;
        #pragma unroll
        for (int s = 0; s < 2; ++s) {
            float4 u = *(const float4*)(xp + s * 32);
            float4 v = *(const float4*)(xp + s * 32 + 4);
            s16x8 a;
            a[0] = bfb(u.x); a[1] = bfb(u.y); a[2] = bfb(u.z); a[3] = bfb(u.w);
            a[4] = bfb(v.x); a[5] = bfb(v.y); a[6] = bfb(v.z); a[7] = bfb(v.w);
            aF[rt][s] = a;
        }
    }

    // ---- top-2 state: slot = rt*4 + reg -> row rt*16 + g*4 + reg ----
    float tb1[16], tb2[16];
    int   tix[16];
    #pragma unroll
    for (int sl = 0; sl < 16; ++sl) { tb1[sl] = 1e30f; tb2[sl] = 1e30f; tix[sl] = 0; }

    const char* ebp = EB + l15 * 128 + g * 16;   // per-lane base
    s16x8 b0 = *(const s16x8*)(ebp);
    s16x8 b1 = *(const s16x8*)(ebp + 64);
    float ckv = ck[l15];
    int kcur = l15;

    for (int tk = 0; tk < 64; ++tk) {
        s16x8 c0 = b0, c1 = b1;
        float cck = ckv;
        // prefetch next tile (pad region beyond tk=63; values unused)
        b0  = *(const s16x8*)(ebp + (tk + 1) * 2048);
        b1  = *(const s16x8*)(ebp + (tk + 1) * 2048 + 64);
        ckv = ck[(tk + 1) * 16 + l15];

        #pragma unroll
        for (int rt = 0; rt < 4; ++rt) {
            f32x4 acc = {0.f, 0.f, 0.f, 0.f};
            acc = __builtin_amdgcn_mfma_f32_16x16x32_bf16(aF[rt][0], c0, acc, 0, 0, 0);
            acc = __builtin_amdgcn_mfma_f32_16x16x32_bf16(aF[rt][1], c1, acc, 0, 0, 0);
            #pragma unroll
            for (int r = 0; r < 4; ++r) {
                float s = fmaf(-2.f, acc[r], cck);
                int sl = rt * 4 + r;
                bool cond = s < tb1[sl];
                tb2[sl] = fminf(tb2[sl], fmaxf(tb1[sl], s));
                tb1[sl] = fminf(tb1[sl], s);
                tix[sl] = cond ? kcur : tix[sl];
            }
        }
        kcur += 16;
    }

    // ---- merge top-2 across the 16 lanes of each group ----
    #pragma unroll
    for (int m = 1; m <= 8; m <<= 1) {
        #pragma unroll
        for (int sl = 0; sl < 16; ++sl) {
            float ob1 = __shfl_xor(tb1[sl], m);
            float ob2 = __shfl_xor(tb2[sl], m);
            int   oid = __shfl_xor(tix[sl], m);
            if (ob1 < tb1[sl] || (ob1 == tb1[sl] && oid < tix[sl])) {
                tb2[sl] = fminf(tb1[sl], ob2);
                tb1[sl] = ob1;
                tix[sl] = oid;
            } else {
                tb2[sl] = fminf(tb2[sl], ob1);
            }
        }
    }

    if (l15 == 0) {
        #pragma unroll
        for (int sl = 0; sl < 16; ++sl) {
            int rloc = wv * 64 + (sl >> 2) * 16 + g * 4 + (sl & 3);
            idxbuf[rloc] = tix[sl];
            if (tb2[sl] - tb1[sl] < MARGIN) {
                int slot = atomicAdd(count, 1);
                if (slot < list_cap) list[slot] = rowbase + rloc;
            }
        }
    }
    __syncthreads();

    // ---- fused gather: out[rowbase + r][:] = ET[idx[r]][:] ----
    const float4* ET4 = (const float4*)ET;
    float4* out4 = (float4*)(out + (size_t)rowbase * DIM);
    #pragma unroll
    for (int p = 0; p < 16; ++p) {
        int f = p * 256 + tid;           // 0..4095
        int r = f >> 4, dq = f & 15;
        out4[f] = ET4[idxbuf[r] * 16 + dq];
    }
}

// Emulate the numpy f32 reference chain for ambiguous rows (validated R2).
__global__ void vq_refine(const float* __restrict__ x,
                          const float* __restrict__ ET,
                          const float* __restrict__ ckseq,
                          float* __restrict__ out,
                          const int* __restrict__ count,
                          const int* __restrict__ list, int list_cap) {
    #pragma clang fp contract(off)
    int gtid = blockIdx.x * blockDim.x + threadIdx.x;
    int wave = gtid >> 6;
    int lane = threadIdx.x & 63;
    int nw = (gridDim.x * blockDim.x) >> 6;
    int n = *count;
    if (n > list_cap) n = list_cap;
    for (int w = wave; w < n; w += nw) {
        int row = list[w];
        const float* z = x + (size_t)row * DIM;
        float zr[DIM];
        #pragma unroll
        for (int d = 0; d < DIM; ++d) zr[d] = z[d];

        // ||z||^2: numpy pairwise_sum for n=64 (8-accumulator unrolled)
        float r8[8];
        #pragma unroll
        for (int j = 0; j < 8; ++j) r8[j] = zr[j] * zr[j];
        #pragma unroll
        for (int i = 8; i < 64; i += 8)
            #pragma unroll
            for (int j = 0; j < 8; ++j) {
                float q = zr[i + j] * zr[i + j];
                r8[j] = r8[j] + q;
            }
        float A = ((r8[0] + r8[1]) + (r8[2] + r8[3]))
                + ((r8[4] + r8[5]) + (r8[6] + r8[7]));

        float best = 1e30f;
        int bid = 0x7fffffff;
        for (int j = 0; j < 16; ++j) {
            int k = lane + 64 * j;            // ascending per lane
            const float* e = ET + k * DIM;
            float s = 0.f;                    // BLAS-style sequential FMA chain
            #pragma unroll
            for (int d = 0; d < DIM; ++d)
                s = fmaf(zr[d], e[d], s);
            float t1 = A + ckseq[k];
            float dist = t1 - 2.0f * s;
            if (dist < best) { best = dist; bid = k; }
        }
        for (int off = 32; off; off >>= 1) {
            float ob = __shfl_down(best, off);
            int   oi = __shfl_down(bid, off);
            if (ob < best || (ob == best && oi < bid)) { best = ob; bid = oi; }
        }
        bid = __shfl(bid, 0);
        out[(size_t)row * DIM + lane] = ET[bid * DIM + lane];
    }
}

extern "C" void kernel_launch(void* const* d_in, const int* in_sizes, int n_in,
                              void* d_out, int out_size, void* d_ws, size_t ws_size,
                              hipStream_t stream) {
    const float* x = (const float*)d_in[0];
    const float* E = (const float*)d_in[1];
    float* out = (float*)d_out;

    char* ws = (char*)d_ws;
    float* ET  = (float*)(ws + ET_OFF);
    float* ck  = (float*)(ws + CK_OFF);
    char*  EB  = ws + EB_OFF;
    int*   cnt = (int*)(ws + CNT_OFF);
    int*   lst = (int*)(ws + LIST_OFF);
    long long avail = (long long)ws_size - LIST_OFF;
    int list_cap = avail > 0 ? (int)(avail / 4) : 0;
    if (list_cap > NROWS) list_cap = NROWS;

    hipMemsetAsync(cnt, 0, sizeof(int), stream);
    vq_prep<<<4, 256, 0, stream>>>(E, ET, ck, EB);
    vq_mfma<<<NROWS / 256, 256, 0, stream>>>(x, ck, EB, ET, out, cnt, lst, list_cap);
    vq_refine<<<1024, 256, 0, stream>>>(x, ET, ck, out, cnt, lst, list_cap);
}

// Round 4
// 413.205 us; speedup vs baseline: 1.4743x; 1.4743x over previous
//
#include <hip/hip_runtime.h>
#include <hip/hip_bf16.h>

// VectorQuantiser: x [32,64,64,64] f32, embeddings [64,1024] f32.
// argmin_k ||z - e_k||^2 over K=1024 for N=131072 rows of D=64; out = codewords.
//
//  k0 vq_prep:  E -> ET[k][d] f32; ckseq[k] = sequential f32 sum_d e^2 (numpy
//               axis-0 order); EB = bf16 fragments of (-2*e) in mfma lane order.
//  k1 vq_mfma:  bf16 MFMA computes score = ck - 2*dot directly (C-in = ck,
//               B = -2e). Branchless top-2; rows with gap < MARGIN -> list.
//  k2 vq_refine: exact numpy-f32-chain emulation for flagged rows (validated
//               R2/R3), no per-thread row array (no spill), rewrites rows.

#define NROWS (32 * 64 * 64)   // 131072
#define DIM   64
#define KCB   1024
#define MARGIN 0.008f

// ws layout (bytes):
#define ET_OFF    0           // float[1024*64] = 262144
#define CK_OFF    262144      // float[1024] + pad -> 4352
#define EB_OFF    266496      // bf16 frags: 1024*128 B + pad = 133376
#define CNT_OFF   399872      // int (+pad)
#define LIST_OFF  400128      // int[cap]

typedef float  f32x4 __attribute__((ext_vector_type(4)));
typedef short  s16x8 __attribute__((ext_vector_type(8)));

static __device__ inline short bfb(float f) {   // f32 -> bf16 bits, RNE
    union { float f; unsigned u; } c{f};
    unsigned r = c.u + 0x7fffu + ((c.u >> 16) & 1u);
    return (short)(r >> 16);
}

__global__ void vq_prep(const float* __restrict__ E,
                        float* __restrict__ ET,
                        float* __restrict__ ckseq,
                        char* __restrict__ EB) {
    #pragma clang fp contract(off)
    int n = blockIdx.x * blockDim.x + threadIdx.x;  // codebook col 0..1023
    if (n >= KCB) return;
    float col[DIM];
    float c = 0.f;
    #pragma unroll
    for (int d = 0; d < DIM; ++d) {
        float v = E[d * KCB + n];      // coalesced along n
        col[d] = v;
        ET[n * DIM + d] = v;
        float q = v * v;
        c = c + q;                     // sequential (numpy axis-0 reduce)
    }
    ckseq[n] = c;
    // B-fragments of (-2*e): lane l needs e[s*32 + (l>>4)*8 + j][col], j=0..7.
    // 8 bf16 = 16 B at EB + n*128 + s*64 + g*16. (-2x is exact in fp, so
    // bfb(-2v) == -2*bfb(v): precision identical to unscaled variant.)
    #pragma unroll
    for (int s = 0; s < 2; ++s)
        #pragma unroll
        for (int g = 0; g < 4; ++g) {
            s16x8 w;
            #pragma unroll
            for (int j = 0; j < 8; ++j)
                w[j] = bfb(-2.f * col[s * 32 + g * 8 + j]);
            *(s16x8*)(EB + n * 128 + s * 64 + g * 16) = w;
        }
}

__global__ __launch_bounds__(256, 2)
void vq_mfma(const float* __restrict__ x, const float* __restrict__ ck,
             const char* __restrict__ EB, const float* __restrict__ ET,
             float* __restrict__ out, int* __restrict__ count,
             int* __restrict__ list, int list_cap) {
    __shared__ int idxbuf[256];

    const int tid  = threadIdx.x;
    const int lane = tid & 63;
    const int wv   = tid >> 6;            // wave 0..3
    const int l15  = lane & 15;
    const int g    = lane >> 4;           // 0..3
    const int rowbase = blockIdx.x * 256; // 256 rows per block

    // ---- A fragments: 4 rowtiles x 2 dsteps, f32 -> bf16 in regs ----
    s16x8 aF[4][2];
    #pragma unroll
    for (int rt = 0; rt < 4; ++rt) {
        int row = rowbase + wv * 64 + rt * 16 + l15;
        const float* xp = x + (size_t)row * DIM + g * 8;
        #pragma unroll
        for (int s = 0; s < 2; ++s) {
            float4 u = *(const float4*)(xp + s * 32);
            float4 v = *(const float4*)(xp + s * 32 + 4);
            s16x8 a;
            a[0] = bfb(u.x); a[1] = bfb(u.y); a[2] = bfb(u.z); a[3] = bfb(u.w);
            a[4] = bfb(v.x); a[5] = bfb(v.y); a[6] = bfb(v.z); a[7] = bfb(v.w);
            aF[rt][s] = a;
        }
    }

    // ---- top-2 state: slot = rt*4 + reg -> row rt*16 + g*4 + reg ----
    float tb1[16], tb2[16];
    int   tix[16];
    #pragma unroll
    for (int sl = 0; sl < 16; ++sl) { tb1[sl] = 1e30f; tb2[sl] = 1e30f; tix[sl] = 0; }

    const char* ebp = EB + l15 * 128 + g * 16;   // per-lane base
    s16x8 b0 = *(const s16x8*)(ebp);
    s16x8 b1 = *(const s16x8*)(ebp + 64);
    float ckv = ck[l15];
    int kcur = l15;

    for (int tk = 0; tk < 64; ++tk) {
        s16x8 c0 = b0, c1 = b1;
        float cck = ckv;
        // prefetch next tile (pad region beyond tk=63; values unused)
        b0  = *(const s16x8*)(ebp + (tk + 1) * 2048);
        b1  = *(const s16x8*)(ebp + (tk + 1) * 2048 + 64);
        ckv = ck[(tk + 1) * 16 + l15];

        #pragma unroll
        for (int rt = 0; rt < 4; ++rt) {
            f32x4 acc = {cck, cck, cck, cck};   // C-in = ||e||^2
            acc = __builtin_amdgcn_mfma_f32_16x16x32_bf16(aF[rt][0], c0, acc, 0, 0, 0);
            acc = __builtin_amdgcn_mfma_f32_16x16x32_bf16(aF[rt][1], c1, acc, 0, 0, 0);
            #pragma unroll
            for (int r = 0; r < 4; ++r) {
                float s = acc[r];               // = ck - 2*dot
                int sl = rt * 4 + r;
                bool cond = s < tb1[sl];
                tb2[sl] = fminf(tb2[sl], fmaxf(tb1[sl], s));
                tb1[sl] = fminf(tb1[sl], s);
                tix[sl] = cond ? kcur : tix[sl];
            }
        }
        kcur += 16;
    }

    // ---- merge top-2 across the 16 lanes of each group ----
    #pragma unroll
    for (int m = 1; m <= 8; m <<= 1) {
        #pragma unroll
        for (int sl = 0; sl < 16; ++sl) {
            float ob1 = __shfl_xor(tb1[sl], m);
            float ob2 = __shfl_xor(tb2[sl], m);
            int   oid = __shfl_xor(tix[sl], m);
            if (ob1 < tb1[sl] || (ob1 == tb1[sl] && oid < tix[sl])) {
                tb2[sl] = fminf(tb1[sl], ob2);
                tb1[sl] = ob1;
                tix[sl] = oid;
            } else {
                tb2[sl] = fminf(tb2[sl], ob1);
            }
        }
    }

    if (l15 == 0) {
        #pragma unroll
        for (int sl = 0; sl < 16; ++sl) {
            int rloc = wv * 64 + (sl >> 2) * 16 + g * 4 + (sl & 3);
            idxbuf[rloc] = tix[sl];
            if (tb2[sl] - tb1[sl] < MARGIN) {
                int slot = atomicAdd(count, 1);
                if (slot < list_cap) list[slot] = rowbase + rloc;
            }
        }
    }
    __syncthreads();

    // ---- fused gather: out[rowbase + r][:] = ET[idx[r]][:] ----
    const float4* ET4 = (const float4*)ET;
    float4* out4 = (float4*)(out + (size_t)rowbase * DIM);
    #pragma unroll
    for (int p = 0; p < 16; ++p) {
        int f = p * 256 + tid;           // 0..4095
        int r = f >> 4, dq = f & 15;
        out4[f] = ET4[idxbuf[r] * 16 + dq];
    }
}

// Emulate the numpy f32 reference chain for ambiguous rows (semantics
// validated R2/R3). No per-thread row array -> no scratch spill: z is read
// via same-address float4 broadcast loads (L1-resident, one line per load).
__global__ __launch_bounds__(256)
void vq_refine(const float* __restrict__ x,
               const float* __restrict__ ET,
               const float* __restrict__ ckseq,
               float* __restrict__ out,
               const int* __restrict__ count,
               const int* __restrict__ list, int list_cap) {
    #pragma clang fp contract(off)
    int gtid = blockIdx.x * blockDim.x + threadIdx.x;
    int wave = gtid >> 6;
    int lane = threadIdx.x & 63;
    int nw = (gridDim.x * blockDim.x) >> 6;
    int n = *count;
    if (n > list_cap) n = list_cap;
    for (int w = wave; w < n; w += nw) {
        int row = list[w];
        const f32x4* z4 = (const f32x4*)(x + (size_t)row * DIM);

        // ||z||^2: numpy pairwise_sum for n=64 (8-accumulator unrolled),
        // element order identical to scalar version.
        float r8[8];
        {
            f32x4 a = z4[0], b = z4[1];
            r8[0] = a.x * a.x; r8[1] = a.y * a.y; r8[2] = a.z * a.z; r8[3] = a.w * a.w;
            r8[4] = b.x * b.x; r8[5] = b.y * b.y; r8[6] = b.z * b.z; r8[7] = b.w * b.w;
        }
        #pragma unroll
        for (int gi = 1; gi < 8; ++gi) {
            f32x4 a = z4[gi * 2], b = z4[gi * 2 + 1];
            r8[0] = r8[0] + a.x * a.x; r8[1] = r8[1] + a.y * a.y;
            r8[2] = r8[2] + a.z * a.z; r8[3] = r8[3] + a.w * a.w;
            r8[4] = r8[4] + b.x * b.x; r8[5] = r8[5] + b.y * b.y;
            r8[6] = r8[6] + b.z * b.z; r8[7] = r8[7] + b.w * b.w;
        }
        float A = ((r8[0] + r8[1]) + (r8[2] + r8[3]))
                + ((r8[4] + r8[5]) + (r8[6] + r8[7]));

        float best = 1e30f;
        int bid = 0x7fffffff;
        // two independent k-chains in flight to hide load latency;
        // per-chain arithmetic = sequential fmaf over d (BLAS emulation).
        for (int j = 0; j < 16; j += 2) {
            int k0 = lane + 64 * j;
            int k1 = lane + 64 * (j + 1);
            const f32x4* e0 = (const f32x4*)(ET + (size_t)k0 * DIM);
            const f32x4* e1 = (const f32x4*)(ET + (size_t)k1 * DIM);
            float s0 = 0.f, s1 = 0.f;
            #pragma unroll 4
            for (int q = 0; q < 16; ++q) {
                f32x4 zv = z4[q];
                f32x4 ev0 = e0[q], ev1 = e1[q];
                s0 = fmaf(zv.x, ev0.x, s0); s1 = fmaf(zv.x, ev1.x, s1);
                s0 = fmaf(zv.y, ev0.y, s0); s1 = fmaf(zv.y, ev1.y, s1);
                s0 = fmaf(zv.z, ev0.z, s0); s1 = fmaf(zv.z, ev1.z, s1);
                s0 = fmaf(zv.w, ev0.w, s0); s1 = fmaf(zv.w, ev1.w, s1);
            }
            float t0 = A + ckseq[k0];
            float d0 = t0 - 2.0f * s0;
            float t1 = A + ckseq[k1];
            float d1 = t1 - 2.0f * s1;
            if (d0 < best) { best = d0; bid = k0; }   // k0 < k1: order kept
            if (d1 < best) { best = d1; bid = k1; }
        }
        for (int off = 32; off; off >>= 1) {
            float ob = __shfl_down(best, off);
            int   oi = __shfl_down(bid, off);
            if (ob < best || (ob == best && oi < bid)) { best = ob; bid = oi; }
        }
        bid = __shfl(bid, 0);
        out[(size_t)row * DIM + lane] = ET[bid * DIM + lane];
    }
}

extern "C" void kernel_launch(void* const* d_in, const int* in_sizes, int n_in,
                              void* d_out, int out_size, void* d_ws, size_t ws_size,
                              hipStream_t stream) {
    const float* x = (const float*)d_in[0];
    const float* E = (const float*)d_in[1];
    float* out = (float*)d_out;

    char* ws = (char*)d_ws;
    float* ET  = (float*)(ws + ET_OFF);
    float* ck  = (float*)(ws + CK_OFF);
    char*  EB  = ws + EB_OFF;
    int*   cnt = (int*)(ws + CNT_OFF);
    int*   lst = (int*)(ws + LIST_OFF);
    long long avail = (long long)ws_size - LIST_OFF;
    int list_cap = avail > 0 ? (int)(avail / 4) : 0;
    if (list_cap > NROWS) list_cap = NROWS;

    hipMemsetAsync(cnt, 0, sizeof(int), stream);
    vq_prep<<<4, 256, 0, stream>>>(E, ET, ck, EB);
    vq_mfma<<<NROWS / 256, 256, 0, stream>>>(x, ck, EB, ET, out, cnt, lst, list_cap);
    vq_refine<<<1024, 256, 0, stream>>>(x, ET, ck, out, cnt, lst, list_cap);
}

// Round 5
// 184.998 us; speedup vs baseline: 3.2930x; 2.2336x over previous
//
#include <hip/hip_runtime.h>
#include <hip/hip_bf16.h>

// VectorQuantiser: x [32,64,64,64] f32, embeddings [64,1024] f32.
// argmin_k ||z - e_k||^2 over K=1024 for N=131072 rows of D=64; out = codewords.
//
//  k0 vq_prep:  ET[k][d] f32; ckseq[k] = sequential f32 sum e^2 (numpy order);
//               EB = bf16 hi/lo fragments of (-2e) in mfma lane order.
//  k1 vq_mfma:  score = ck - 2*dot via 3-product bf16 hi/lo MFMA (err ~1e-5).
//               C-in = ck. Branchless top-2; gap < MARGIN -> refine list.
//  k2 vq_refine: exact numpy-f32-chain emulation for flagged rows (~140),
//               16 parallel k-chains per lane for MLP.

#define NROWS (32 * 64 * 64)   // 131072
#define DIM   64
#define KCB   1024
#define MARGIN 1.5e-4f

// ws layout (bytes):
#define ET_OFF    0           // float[1024*64] = 262144
#define CK_OFF    262144      // float[1088] pad  -> 4352
#define EB_OFF    266496      // 65 tiles * 4096 B = 266240 (64 + 1 prefetch pad)
#define CNT_OFF   532736      // int (+pad)
#define LIST_OFF  532992      // int[cap]

typedef float  f32x4 __attribute__((ext_vector_type(4)));
typedef short  s16x8 __attribute__((ext_vector_type(8)));

static __device__ inline short bfb(float f) {   // f32 -> bf16 bits, RNE
    union { float f; unsigned u; } c{f};
    unsigned r = c.u + 0x7fffu + ((c.u >> 16) & 1u);
    return (short)(r >> 16);
}
static __device__ inline float bf2f(short b) {  // bf16 bits -> f32
    union { unsigned u; float f; } c{(unsigned)(unsigned short)b << 16};
    return c.f;
}

__global__ void vq_prep(const float* __restrict__ E,
                        float* __restrict__ ET,
                        float* __restrict__ ckseq,
                        char* __restrict__ EB) {
    #pragma clang fp contract(off)
    int n = blockIdx.x * blockDim.x + threadIdx.x;  // codebook col 0..1023
    if (n >= KCB) return;
    float col[DIM];
    float c = 0.f;
    #pragma unroll
    for (int d = 0; d < DIM; ++d) {
        float v = E[d * KCB + n];      // coalesced along n
        col[d] = v;
        ET[n * DIM + d] = v;
        float q = v * v;
        c = c + q;                     // sequential (numpy axis-0 reduce)
    }
    ckseq[n] = c;
    // hi/lo fragments of m = -2*e (exact scale). Lane l of a wave consumes
    // d = s*32 + (l>>4)*8 + j, j=0..7 contiguous. Tile tk = n>>4 holds k%16=l15.
    int tk = n >> 4, l15 = n & 15;
    char* base = EB + tk * 4096 + l15 * 128;
    #pragma unroll
    for (int s = 0; s < 2; ++s)
        #pragma unroll
        for (int g = 0; g < 4; ++g) {
            s16x8 wh, wl;
            #pragma unroll
            for (int j = 0; j < 8; ++j) {
                float m = -2.f * col[s * 32 + g * 8 + j];
                short h = bfb(m);
                float r = m - bf2f(h);          // exact (Sterbenz-ish)
                wh[j] = h;
                wl[j] = bfb(r);
            }
            *(s16x8*)(base + s * 64 + g * 16) = wh;          // eh
            *(s16x8*)(base + 2048 + s * 64 + g * 16) = wl;   // el
        }
}

__global__ __launch_bounds__(256, 2)
void vq_mfma(const float* __restrict__ x, const float* __restrict__ ck,
             const char* __restrict__ EB, const float* __restrict__ ET,
             float* __restrict__ out, int* __restrict__ count,
             int* __restrict__ list, int list_cap) {
    __shared__ int idxbuf[256];

    const int tid  = threadIdx.x;
    const int lane = tid & 63;
    const int wv   = tid >> 6;            // wave 0..3
    const int l15  = lane & 15;
    const int g    = lane >> 4;           // 0..3
    const int rowbase = blockIdx.x * 256; // 256 rows per block

    // ---- A fragments hi/lo: 4 rowtiles x 2 dsteps ----
    s16x8 aH[4][2], aL[4][2];
    #pragma unroll
    for (int rt = 0; rt < 4; ++rt) {
        int row = rowbase + wv * 64 + rt * 16 + l15;
        const float* xp = x + (size_t)row * DIM + g * 8;
        #pragma unroll
        for (int s = 0; s < 2; ++s) {
            float val[8];
            float4 u = *(const float4*)(xp + s * 32);
            float4 v = *(const float4*)(xp + s * 32 + 4);
            val[0] = u.x; val[1] = u.y; val[2] = u.z; val[3] = u.w;
            val[4] = v.x; val[5] = v.y; val[6] = v.z; val[7] = v.w;
            s16x8 h, l;
            #pragma unroll
            for (int j = 0; j < 8; ++j) {
                short hb = bfb(val[j]);
                h[j] = hb;
                l[j] = bfb(val[j] - bf2f(hb));
            }
            aH[rt][s] = h;
            aL[rt][s] = l;
        }
    }

    // ---- top-2 state: slot = rt*4 + reg -> row rt*16 + g*4 + reg ----
    float tb1[16], tb2[16];
    int   tix[16];
    #pragma unroll
    for (int sl = 0; sl < 16; ++sl) { tb1[sl] = 1e30f; tb2[sl] = 1e30f; tix[sl] = 0; }

    const char* ebp = EB + l15 * 128 + g * 16;   // per-lane base
    s16x8 bh0 = *(const s16x8*)(ebp);
    s16x8 bh1 = *(const s16x8*)(ebp + 64);
    s16x8 bl0 = *(const s16x8*)(ebp + 2048);
    s16x8 bl1 = *(const s16x8*)(ebp + 2112);
    float ckv = ck[l15];
    int kcur = l15;

    for (int tk = 0; tk < 64; ++tk) {
        s16x8 ch0 = bh0, ch1 = bh1, cl0 = bl0, cl1 = bl1;
        float cck = ckv;
        // prefetch next tile (pad region beyond tk=63; values unused)
        const char* nb = ebp + (tk + 1) * 4096;
        bh0 = *(const s16x8*)(nb);
        bh1 = *(const s16x8*)(nb + 64);
        bl0 = *(const s16x8*)(nb + 2048);
        bl1 = *(const s16x8*)(nb + 2112);
        ckv = ck[(tk + 1) * 16 + l15];

        #pragma unroll
        for (int rt = 0; rt < 4; ++rt) {
            f32x4 acc = {cck, cck, cck, cck};   // C-in = ||e||^2
            acc = __builtin_amdgcn_mfma_f32_16x16x32_bf16(aH[rt][0], ch0, acc, 0, 0, 0);
            acc = __builtin_amdgcn_mfma_f32_16x16x32_bf16(aH[rt][1], ch1, acc, 0, 0, 0);
            acc = __builtin_amdgcn_mfma_f32_16x16x32_bf16(aL[rt][0], ch0, acc, 0, 0, 0);
            acc = __builtin_amdgcn_mfma_f32_16x16x32_bf16(aL[rt][1], ch1, acc, 0, 0, 0);
            acc = __builtin_amdgcn_mfma_f32_16x16x32_bf16(aH[rt][0], cl0, acc, 0, 0, 0);
            acc = __builtin_amdgcn_mfma_f32_16x16x32_bf16(aH[rt][1], cl1, acc, 0, 0, 0);
            #pragma unroll
            for (int r = 0; r < 4; ++r) {
                float s = acc[r];               // = ck - 2*dot (hi/lo accurate)
                int sl = rt * 4 + r;
                bool cond = s < tb1[sl];
                tb2[sl] = fminf(tb2[sl], fmaxf(tb1[sl], s));
                tb1[sl] = fminf(tb1[sl], s);
                tix[sl] = cond ? kcur : tix[sl];
            }
        }
        kcur += 16;
    }

    // ---- merge top-2 across the 16 lanes of each group ----
    #pragma unroll
    for (int m = 1; m <= 8; m <<= 1) {
        #pragma unroll
        for (int sl = 0; sl < 16; ++sl) {
            float ob1 = __shfl_xor(tb1[sl], m);
            float ob2 = __shfl_xor(tb2[sl], m);
            int   oid = __shfl_xor(tix[sl], m);
            if (ob1 < tb1[sl] || (ob1 == tb1[sl] && oid < tix[sl])) {
                tb2[sl] = fminf(tb1[sl], ob2);
                tb1[sl] = ob1;
                tix[sl] = oid;
            } else {
                tb2[sl] = fminf(tb2[sl], ob1);
            }
        }
    }

    if (l15 == 0) {
        #pragma unroll
        for (int sl = 0; sl < 16; ++sl) {
            int rloc = wv * 64 + (sl >> 2) * 16 + g * 4 + (sl & 3);
            idxbuf[rloc] = tix[sl];
            if (tb2[sl] - tb1[sl] < MARGIN) {
                int slot = atomicAdd(count, 1);
                if (slot < list_cap) list[slot] = rowbase + rloc;
            }
        }
    }
    __syncthreads();

    // ---- fused gather: out[rowbase + r][:] = ET[idx[r]][:] ----
    const float4* ET4 = (const float4*)ET;
    float4* out4 = (float4*)(out + (size_t)rowbase * DIM);
    #pragma unroll
    for (int p = 0; p < 16; ++p) {
        int f = p * 256 + tid;           // 0..4095
        int r = f >> 4, dq = f & 15;
        out4[f] = ET4[idxbuf[r] * 16 + dq];
    }
}

// Exact numpy-f32-chain emulation for flagged rows (semantics validated
// R2-R4). 16 independent k-chains per lane -> 16 loads in flight.
__global__ __launch_bounds__(256)
void vq_refine(const float* __restrict__ x,
               const float* __restrict__ ET,
               const float* __restrict__ ckseq,
               float* __restrict__ out,
               const int* __restrict__ count,
               const int* __restrict__ list, int list_cap) {
    #pragma clang fp contract(off)
    int gtid = blockIdx.x * blockDim.x + threadIdx.x;
    int wave = gtid >> 6;
    int lane = threadIdx.x & 63;
    int nw = (gridDim.x * blockDim.x) >> 6;
    int n = *count;
    if (n > list_cap) n = list_cap;
    for (int w = wave; w < n; w += nw) {
        int row = list[w];
        const f32x4* z4 = (const f32x4*)(x + (size_t)row * DIM);

        // ||z||^2: numpy pairwise_sum for n=64 (8-accumulator unrolled)
        float r8[8];
        {
            f32x4 a = z4[0], b = z4[1];
            r8[0] = a.x * a.x; r8[1] = a.y * a.y; r8[2] = a.z * a.z; r8[3] = a.w * a.w;
            r8[4] = b.x * b.x; r8[5] = b.y * b.y; r8[6] = b.z * b.z; r8[7] = b.w * b.w;
        }
        #pragma unroll
        for (int gi = 1; gi < 8; ++gi) {
            f32x4 a = z4[gi * 2], b = z4[gi * 2 + 1];
            r8[0] = r8[0] + a.x * a.x; r8[1] = r8[1] + a.y * a.y;
            r8[2] = r8[2] + a.z * a.z; r8[3] = r8[3] + a.w * a.w;
            r8[4] = r8[4] + b.x * b.x; r8[5] = r8[5] + b.y * b.y;
            r8[6] = r8[6] + b.z * b.z; r8[7] = r8[7] + b.w * b.w;
        }
        float A = ((r8[0] + r8[1]) + (r8[2] + r8[3]))
                + ((r8[4] + r8[5]) + (r8[6] + r8[7]));

        // 16 chains (k = lane + 64*j), each a sequential fmaf over d=0..63
        float s[16];
        #pragma unroll
        for (int j = 0; j < 16; ++j) s[j] = 0.f;
        #pragma unroll
        for (int q = 0; q < 16; ++q) {
            f32x4 zv = z4[q];
            #pragma unroll
            for (int j = 0; j < 16; ++j) {
                f32x4 ev = *(const f32x4*)(ET + (size_t)(lane + 64 * j) * DIM + q * 4);
                s[j] = fmaf(zv.x, ev.x, s[j]);
                s[j] = fmaf(zv.y, ev.y, s[j]);
                s[j] = fmaf(zv.z, ev.z, s[j]);
                s[j] = fmaf(zv.w, ev.w, s[j]);
            }
        }

        float best = 1e30f;
        int bid = 0x7fffffff;
        #pragma unroll
        for (int j = 0; j < 16; ++j) {        // j ascending -> first-index kept
            int k = lane + 64 * j;
            float t = A + ckseq[k];
            float d = t - 2.0f * s[j];
            if (d < best) { best = d; bid = k; }
        }
        for (int off = 32; off; off >>= 1) {
            float ob = __shfl_down(best, off);
            int   oi = __shfl_down(bid, off);
            if (ob < best || (ob == best && oi < bid)) { best = ob; bid = oi; }
        }
        bid = __shfl(bid, 0);
        out[(size_t)row * DIM + lane] = ET[bid * DIM + lane];
    }
}

extern "C" void kernel_launch(void* const* d_in, const int* in_sizes, int n_in,
                              void* d_out, int out_size, void* d_ws, size_t ws_size,
                              hipStream_t stream) {
    const float* x = (const float*)d_in[0];
    const float* E = (const float*)d_in[1];
    float* out = (float*)d_out;

    char* ws = (char*)d_ws;
    float* ET  = (float*)(ws + ET_OFF);
    float* ck  = (float*)(ws + CK_OFF);
    char*  EB  = ws + EB_OFF;
    int*   cnt = (int*)(ws + CNT_OFF);
    int*   lst = (int*)(ws + LIST_OFF);
    long long avail = (long long)ws_size - LIST_OFF;
    int list_cap = avail > 0 ? (int)(avail / 4) : 0;
    if (list_cap > NROWS) list_cap = NROWS;

    hipMemsetAsync(cnt, 0, sizeof(int), stream);
    vq_prep<<<4, 256, 0, stream>>>(E, ET, ck, EB);
    vq_mfma<<<NROWS / 256, 256, 0, stream>>>(x, ck, EB, ET, out, cnt, lst, list_cap);
    vq_refine<<<1024, 256, 0, stream>>>(x, ET, ck, out, cnt, lst, list_cap);
}

// Round 6
// 110.279 us; speedup vs baseline: 5.5242x; 1.6775x over previous
//
#include <hip/hip_runtime.h>
#include <hip/hip_bf16.h>

// VectorQuantiser: x [32,64,64,64] f32, embeddings [64,1024] f32.
// argmin_k ||z - e_k||^2 over K=1024 for N=131072 rows of D=64; out = codewords.
//
//  k0 vq_prep:   ET[k][d] f32; ckseq[k] = sequential f32 sum e^2 (numpy order);
//                EB = bf16 hi/lo fragments of (-2e) in mfma lane order.
//  k1 vq_mfma:   score = ck - 2*dot via 3-product bf16 hi/lo MFMA (err ~2e-6).
//                Branchless top-2; gap < MARGIN -> list + rowbest init.
//  k2 vq_refineB: per (row, 64-k chunk) wave: exact numpy-f32 chain dist
//                (coalesced E[d][k] loads), wave-reduce, atomicMin packed key.
//  k3 vq_refineC: per row: unpack winning k, gather codeword, rewrite row.

#define NROWS (32 * 64 * 64)   // 131072
#define DIM   64
#define KCB   1024
#define MARGIN 1.5e-4f

// ws layout (bytes):
#define ET_OFF    0           // float[1024*64] = 262144
#define CK_OFF    262144      // float[1088] pad  -> 4352
#define EB_OFF    266496      // 65 tiles * 4096 B = 266240
#define CNT_OFF   532736      // int (+pad)
#define RB_OFF    532992      // u64[8192] rowbest = 65536
#define LIST_OFF  598528      // int[cap]
#define RB_CAP    8192

typedef float  f32x4 __attribute__((ext_vector_type(4)));
typedef short  s16x8 __attribute__((ext_vector_type(8)));

static __device__ inline short bfb(float f) {   // f32 -> bf16 bits, RNE
    union { float f; unsigned u; } c{f};
    unsigned r = c.u + 0x7fffu + ((c.u >> 16) & 1u);
    return (short)(r >> 16);
}
static __device__ inline float bf2f(short b) {  // bf16 bits -> f32
    union { unsigned u; float f; } c{(unsigned)(unsigned short)b << 16};
    return c.f;
}

__global__ void vq_prep(const float* __restrict__ E,
                        float* __restrict__ ET,
                        float* __restrict__ ckseq,
                        char* __restrict__ EB) {
    #pragma clang fp contract(off)
    int n = blockIdx.x * blockDim.x + threadIdx.x;  // codebook col 0..1023
    if (n >= KCB) return;
    float col[DIM];
    float c = 0.f;
    #pragma unroll
    for (int d = 0; d < DIM; ++d) {
        float v = E[d * KCB + n];      // coalesced along n
        col[d] = v;
        ET[n * DIM + d] = v;
        float q = v * v;
        c = c + q;                     // sequential (numpy axis-0 reduce)
    }
    ckseq[n] = c;
    // hi/lo fragments of m = -2*e (exact scale). Lane l of a wave consumes
    // d = s*32 + (l>>4)*8 + j, j=0..7. Tile tk = n>>4, column l15 = n&15.
    int tk = n >> 4, l15 = n & 15;
    char* base = EB + tk * 4096 + l15 * 128;
    #pragma unroll
    for (int s = 0; s < 2; ++s)
        #pragma unroll
        for (int g = 0; g < 4; ++g) {
            s16x8 wh, wl;
            #pragma unroll
            for (int j = 0; j < 8; ++j) {
                float m = -2.f * col[s * 32 + g * 8 + j];
                short h = bfb(m);
                float r = m - bf2f(h);          // exact residual
                wh[j] = h;
                wl[j] = bfb(r);
            }
            *(s16x8*)(base + s * 64 + g * 16) = wh;          // hi
            *(s16x8*)(base + 2048 + s * 64 + g * 16) = wl;   // lo
        }
}

__global__ __launch_bounds__(256, 2)
void vq_mfma(const float* __restrict__ x, const float* __restrict__ ck,
             const char* __restrict__ EB, const float* __restrict__ ET,
             float* __restrict__ out, int* __restrict__ count,
             int* __restrict__ list, unsigned long long* __restrict__ rowbest,
             int list_cap) {
    __shared__ int idxbuf[256];

    const int tid  = threadIdx.x;
    const int lane = tid & 63;
    const int wv   = tid >> 6;            // wave 0..3
    const int l15  = lane & 15;
    const int g    = lane >> 4;           // 0..3
    const int rowbase = blockIdx.x * 256; // 256 rows per block

    // ---- A fragments hi/lo: 4 rowtiles x 2 dsteps ----
    s16x8 aH[4][2], aL[4][2];
    #pragma unroll
    for (int rt = 0; rt < 4; ++rt) {
        int row = rowbase + wv * 64 + rt * 16 + l15;
        const float* xp = x + (size_t)row * DIM + g * 8;
        #pragma unroll
        for (int s = 0; s < 2; ++s) {
            float val[8];
            float4 u = *(const float4*)(xp + s * 32);
            float4 v = *(const float4*)(xp + s * 32 + 4);
            val[0] = u.x; val[1] = u.y; val[2] = u.z; val[3] = u.w;
            val[4] = v.x; val[5] = v.y; val[6] = v.z; val[7] = v.w;
            s16x8 h, l;
            #pragma unroll
            for (int j = 0; j < 8; ++j) {
                short hb = bfb(val[j]);
                h[j] = hb;
                l[j] = bfb(val[j] - bf2f(hb));
            }
            aH[rt][s] = h;
            aL[rt][s] = l;
        }
    }

    // ---- top-2 state: slot = rt*4 + reg -> row rt*16 + g*4 + reg ----
    float tb1[16], tb2[16];
    int   tix[16];
    #pragma unroll
    for (int sl = 0; sl < 16; ++sl) { tb1[sl] = 1e30f; tb2[sl] = 1e30f; tix[sl] = 0; }

    const char* ebp = EB + l15 * 128 + g * 16;   // per-lane base
    s16x8 bh0 = *(const s16x8*)(ebp);
    s16x8 bh1 = *(const s16x8*)(ebp + 64);
    s16x8 bl0 = *(const s16x8*)(ebp + 2048);
    s16x8 bl1 = *(const s16x8*)(ebp + 2112);
    float ckv = ck[l15];
    int kcur = l15;

    for (int tk = 0; tk < 64; ++tk) {
        s16x8 ch0 = bh0, ch1 = bh1, cl0 = bl0, cl1 = bl1;
        float cck = ckv;
        // prefetch next tile (pad region beyond tk=63; values unused)
        const char* nb = ebp + (tk + 1) * 4096;
        bh0 = *(const s16x8*)(nb);
        bh1 = *(const s16x8*)(nb + 64);
        bl0 = *(const s16x8*)(nb + 2048);
        bl1 = *(const s16x8*)(nb + 2112);
        ckv = ck[(tk + 1) * 16 + l15];

        #pragma unroll
        for (int rt = 0; rt < 4; ++rt) {
            f32x4 acc = {cck, cck, cck, cck};   // C-in = ||e||^2
            acc = __builtin_amdgcn_mfma_f32_16x16x32_bf16(aH[rt][0], ch0, acc, 0, 0, 0);
            acc = __builtin_amdgcn_mfma_f32_16x16x32_bf16(aH[rt][1], ch1, acc, 0, 0, 0);
            acc = __builtin_amdgcn_mfma_f32_16x16x32_bf16(aL[rt][0], ch0, acc, 0, 0, 0);
            acc = __builtin_amdgcn_mfma_f32_16x16x32_bf16(aL[rt][1], ch1, acc, 0, 0, 0);
            acc = __builtin_amdgcn_mfma_f32_16x16x32_bf16(aH[rt][0], cl0, acc, 0, 0, 0);
            acc = __builtin_amdgcn_mfma_f32_16x16x32_bf16(aH[rt][1], cl1, acc, 0, 0, 0);
            #pragma unroll
            for (int r = 0; r < 4; ++r) {
                float s = acc[r];               // = ck - 2*dot (hi/lo accurate)
                int sl = rt * 4 + r;
                bool cond = s < tb1[sl];
                tb2[sl] = fminf(tb2[sl], fmaxf(tb1[sl], s));
                tb1[sl] = fminf(tb1[sl], s);
                tix[sl] = cond ? kcur : tix[sl];
            }
        }
        kcur += 16;
    }

    // ---- merge top-2 across the 16 lanes of each group ----
    #pragma unroll
    for (int m = 1; m <= 8; m <<= 1) {
        #pragma unroll
        for (int sl = 0; sl < 16; ++sl) {
            float ob1 = __shfl_xor(tb1[sl], m);
            float ob2 = __shfl_xor(tb2[sl], m);
            int   oid = __shfl_xor(tix[sl], m);
            if (ob1 < tb1[sl] || (ob1 == tb1[sl] && oid < tix[sl])) {
                tb2[sl] = fminf(tb1[sl], ob2);
                tb1[sl] = ob1;
                tix[sl] = oid;
            } else {
                tb2[sl] = fminf(tb2[sl], ob1);
            }
        }
    }

    if (l15 == 0) {
        #pragma unroll
        for (int sl = 0; sl < 16; ++sl) {
            int rloc = wv * 64 + (sl >> 2) * 16 + g * 4 + (sl & 3);
            idxbuf[rloc] = tix[sl];
            if (tb2[sl] - tb1[sl] < MARGIN) {
                int slot = atomicAdd(count, 1);
                if (slot < list_cap) {
                    list[slot] = rowbase + rloc;
                    rowbest[slot] = ~0ull;      // init for refineB's atomicMin
                }
            }
        }
    }
    __syncthreads();

    // ---- fused gather: out[rowbase + r][:] = ET[idx[r]][:] ----
    const float4* ET4 = (const float4*)ET;
    float4* out4 = (float4*)(out + (size_t)rowbase * DIM);
    #pragma unroll
    for (int p = 0; p < 16; ++p) {
        int f = p * 256 + tid;           // 0..4095
        int r = f >> 4, dq = f & 15;
        out4[f] = ET4[idxbuf[r] * 16 + dq];
    }
}

// Exact numpy-f32-chain distance for flagged rows (semantics validated
// R2-R5). One wave per (row, 64-k chunk): lane = k, E read in ORIGINAL
// [d][k] layout -> coalesced 4B/lane, loads independent (only the fmaf
// chain is serial). Wave-reduce to packed (ordbits(dist)<<32)|k key, one
// atomicMin per wave -> bit-exact first-index argmin across chunks.
__global__ __launch_bounds__(256)
void vq_refineB(const float* __restrict__ x, const float* __restrict__ E,
                const float* __restrict__ ckseq,
                const int* __restrict__ count, const int* __restrict__ list,
                unsigned long long* __restrict__ rowbest, int list_cap) {
    #pragma clang fp contract(off)
    int n = *count;
    if (n > list_cap) n = list_cap;
    int items = n * 16;
    int gw = (blockIdx.x * blockDim.x + threadIdx.x) >> 6;
    int lane = threadIdx.x & 63;
    int nw = (gridDim.x * blockDim.x) >> 6;
    for (int it = gw; it < items; it += nw) {
        int slot = it >> 4, chunk = it & 15;
        int row = list[slot];
        const f32x4* z4 = (const f32x4*)(x + (size_t)row * DIM);

        // ||z||^2: numpy pairwise_sum n=64 (8-acc unrolled), validated order
        float r8[8];
        {
            f32x4 a = z4[0], b = z4[1];
            r8[0] = a.x * a.x; r8[1] = a.y * a.y; r8[2] = a.z * a.z; r8[3] = a.w * a.w;
            r8[4] = b.x * b.x; r8[5] = b.y * b.y; r8[6] = b.z * b.z; r8[7] = b.w * b.w;
        }
        #pragma unroll
        for (int gi = 1; gi < 8; ++gi) {
            f32x4 a = z4[gi * 2], b = z4[gi * 2 + 1];
            r8[0] = r8[0] + a.x * a.x; r8[1] = r8[1] + a.y * a.y;
            r8[2] = r8[2] + a.z * a.z; r8[3] = r8[3] + a.w * a.w;
            r8[4] = r8[4] + b.x * b.x; r8[5] = r8[5] + b.y * b.y;
            r8[6] = r8[6] + b.z * b.z; r8[7] = r8[7] + b.w * b.w;
        }
        float A = ((r8[0] + r8[1]) + (r8[2] + r8[3]))
                + ((r8[4] + r8[5]) + (r8[6] + r8[7]));

        int k = chunk * 64 + lane;
        float s = 0.f;                    // sequential fmaf over d (BLAS emu)
        #pragma unroll
        for (int q = 0; q < 16; ++q) {
            f32x4 zv = z4[q];
            s = fmaf(zv.x, E[(4 * q + 0) * KCB + k], s);
            s = fmaf(zv.y, E[(4 * q + 1) * KCB + k], s);
            s = fmaf(zv.z, E[(4 * q + 2) * KCB + k], s);
            s = fmaf(zv.w, E[(4 * q + 3) * KCB + k], s);
        }
        float t = A + ckseq[k];
        float dist = t - 2.0f * s;

        // pack: monotone float ordbits in high 32, k in low 32
        unsigned u = __float_as_uint(dist);
        unsigned ord = u ^ ((u & 0x80000000u) ? 0xFFFFFFFFu : 0x80000000u);
        unsigned long long key = ((unsigned long long)ord << 32) | (unsigned)k;
        #pragma unroll
        for (int off = 32; off; off >>= 1) {
            unsigned long long ok = __shfl_xor(key, off);
            key = ok < key ? ok : key;
        }
        if (lane == 0) atomicMin(rowbest + slot, key);
    }
}

__global__ void vq_refineC(const float* __restrict__ ET,
                           float* __restrict__ out,
                           const int* __restrict__ count,
                           const int* __restrict__ list,
                           const unsigned long long* __restrict__ rowbest,
                           int list_cap) {
    int n = *count;
    if (n > list_cap) n = list_cap;
    int gw = (blockIdx.x * blockDim.x + threadIdx.x) >> 6;
    int lane = threadIdx.x & 63;
    int nw = (gridDim.x * blockDim.x) >> 6;
    for (int slot = gw; slot < n; slot += nw) {
        int row = list[slot];
        unsigned k = (unsigned)(rowbest[slot] & 0xFFFFFFFFu);
        out[(size_t)row * DIM + lane] = ET[(size_t)k * DIM + lane];
    }
}

extern "C" void kernel_launch(void* const* d_in, const int* in_sizes, int n_in,
                              void* d_out, int out_size, void* d_ws, size_t ws_size,
                              hipStream_t stream) {
    const float* x = (const float*)d_in[0];
    const float* E = (const float*)d_in[1];
    float* out = (float*)d_out;

    char* ws = (char*)d_ws;
    float* ET  = (float*)(ws + ET_OFF);
    float* ck  = (float*)(ws + CK_OFF);
    char*  EB  = ws + EB_OFF;
    int*   cnt = (int*)(ws + CNT_OFF);
    unsigned long long* rb = (unsigned long long*)(ws + RB_OFF);
    int*   lst = (int*)(ws + LIST_OFF);
    long long avail = (long long)ws_size - LIST_OFF;
    int list_cap = avail > 0 ? (int)(avail / 4) : 0;
    if (list_cap > RB_CAP) list_cap = RB_CAP;

    hipMemsetAsync(cnt, 0, sizeof(int), stream);
    vq_prep<<<4, 256, 0, stream>>>(E, ET, ck, EB);
    vq_mfma<<<NROWS / 256, 256, 0, stream>>>(x, ck, EB, ET, out, cnt, lst, rb, list_cap);
    vq_refineB<<<512, 256, 0, stream>>>(x, E, ck, cnt, lst, rb, list_cap);
    vq_refineC<<<128, 256, 0, stream>>>(ET, out, cnt, lst, rb, list_cap);
}

// Round 7
// 93.201 us; speedup vs baseline: 6.5365x; 1.1832x over previous
//
#include <hip/hip_runtime.h>
#include <hip/hip_bf16.h>

// VectorQuantiser: x [32,64,64,64] f32, embeddings [64,1024] f32.
// argmin_k ||z - e_k||^2 over K=1024 for N=131072 rows of D=64; out = codewords.
//
//  k0 vq_prep:   ET[k][d] f32; ckseq[k] = sequential f32 sum e^2 (numpy order);
//                EB = bf16 hi/lo fragments of (-2e), lane-linear per 16-col tile.
//  k1 vq_mfma:   score = ck - 2*dot via 3-product bf16 hi/lo MFMA (err ~2e-6).
//                32 rows/wave, B via LDS double-buffer, 4 blocks/CU.
//                Branchless top-2; gap < MARGIN -> list + rowbest init.
//  k2 vq_refineB: per (row, 64-k chunk) wave: exact numpy-f32 chain dist
//                (coalesced E[d][k] loads), wave-reduce, atomicMin packed key.
//  k3 vq_refineC: per row: unpack winning k, gather codeword, rewrite row.

#define NROWS (32 * 64 * 64)   // 131072
#define DIM   64
#define KCB   1024
#define MARGIN 1.5e-4f

// ws layout (bytes):
#define ET_OFF    0           // float[1024*64] = 262144
#define CK_OFF    262144      // float[1088] pad -> 4352
#define EB_OFF    266496      // 64 tiles * 4096 B = 262144
#define CNT_OFF   528640      // int (+pad)
#define RB_OFF    528896      // u64[8192] rowbest = 65536
#define LIST_OFF  594432      // int[cap]
#define RB_CAP    8192

typedef float  f32x4 __attribute__((ext_vector_type(4)));
typedef short  s16x8 __attribute__((ext_vector_type(8)));

static __device__ inline short bfb(float f) {   // f32 -> bf16 bits, RNE
    union { float f; unsigned u; } c{f};
    unsigned r = c.u + 0x7fffu + ((c.u >> 16) & 1u);
    return (short)(r >> 16);
}
static __device__ inline float bf2f(short b) {  // bf16 bits -> f32
    union { unsigned u; float f; } c{(unsigned)(unsigned short)b << 16};
    return c.f;
}

__global__ void vq_prep(const float* __restrict__ E,
                        float* __restrict__ ET,
                        float* __restrict__ ckseq,
                        char* __restrict__ EB) {
    #pragma clang fp contract(off)
    int n = blockIdx.x * blockDim.x + threadIdx.x;  // codebook col 0..1023
    if (n >= KCB) return;
    float col[DIM];
    float c = 0.f;
    #pragma unroll
    for (int d = 0; d < DIM; ++d) {
        float v = E[d * KCB + n];      // coalesced along n
        col[d] = v;
        ET[n * DIM + d] = v;
        float q = v * v;
        c = c + q;                     // sequential (numpy axis-0 reduce)
    }
    ckseq[n] = c;
    // Tile tk = n>>4 (16 cols), 4096 B, LANE-LINEAR layout:
    //   [0,1024):   hi s=0, 16 B per lane, lane = g*16 + l15
    //   [1024,2048): hi s=1 ; [2048,3072): lo s=0 ; [3072,4096): lo s=1
    // Fragment (s,g) holds m = -2*e[d], d = s*32 + g*8 + j (exact scale).
    int tk = n >> 4, l15 = n & 15;
    char* tb = EB + tk * 4096;
    #pragma unroll
    for (int s = 0; s < 2; ++s)
        #pragma unroll
        for (int g = 0; g < 4; ++g) {
            s16x8 wh, wl;
            #pragma unroll
            for (int j = 0; j < 8; ++j) {
                float m = -2.f * col[s * 32 + g * 8 + j];
                short h = bfb(m);
                float r = m - bf2f(h);          // exact residual
                wh[j] = h;
                wl[j] = bfb(r);
            }
            *(s16x8*)(tb + s * 1024 + (g * 16 + l15) * 16) = wh;          // hi
            *(s16x8*)(tb + 2048 + s * 1024 + (g * 16 + l15) * 16) = wl;   // lo
        }
}

__global__ __launch_bounds__(256, 4)
void vq_mfma(const float* __restrict__ x, const float* __restrict__ ck,
             const char* __restrict__ EB, const float* __restrict__ ET,
             float* __restrict__ out, int* __restrict__ count,
             int* __restrict__ list, unsigned long long* __restrict__ rowbest,
             int list_cap) {
    __shared__ alignas(16) char ebuf[2][4096];  // B tile double buffer
    __shared__ float ckls[KCB];
    __shared__ int idxbuf[128];

    const int tid  = threadIdx.x;
    const int lane = tid & 63;
    const int wv   = tid >> 6;            // wave 0..3
    const int l15  = lane & 15;
    const int g    = lane >> 4;           // 0..3
    const int rowbase = blockIdx.x * 128; // 128 rows per block, 32 per wave

    // ---- A fragments hi/lo: 2 rowtiles x 2 dsteps (32 VGPR persistent) ----
    s16x8 aH[2][2], aL[2][2];
    #pragma unroll
    for (int rt = 0; rt < 2; ++rt) {
        int row = rowbase + wv * 32 + rt * 16 + l15;
        const float* xp = x + (size_t)row * DIM + g * 8;
        #pragma unroll
        for (int s = 0; s < 2; ++s) {
            float val[8];
            float4 u = *(const float4*)(xp + s * 32);
            float4 v = *(const float4*)(xp + s * 32 + 4);
            val[0] = u.x; val[1] = u.y; val[2] = u.z; val[3] = u.w;
            val[4] = v.x; val[5] = v.y; val[6] = v.z; val[7] = v.w;
            s16x8 h, l;
            #pragma unroll
            for (int j = 0; j < 8; ++j) {
                short hb = bfb(val[j]);
                h[j] = hb;
                l[j] = bfb(val[j] - bf2f(hb));
            }
            aH[rt][s] = h;
            aL[rt][s] = l;
        }
    }

    // ---- stage ck table + tile 0 into LDS ----
    const float4* ebg = (const float4*)EB;      // EB as float4[64][256]
    ((float4*)ckls)[tid] = ((const float4*)ck)[tid];
    ((float4*)&ebuf[0][0])[tid] = ebg[tid];
    __syncthreads();

    // ---- top-2 state: slot = rt*4 + r -> row rt*16 + g*4 + r ----
    float tb1[8], tb2[8];
    int   tix[8];
    #pragma unroll
    for (int sl = 0; sl < 8; ++sl) { tb1[sl] = 1e30f; tb2[sl] = 1e30f; tix[sl] = 0; }

    int kcur = l15;
    for (int tk = 0; tk < 64; ++tk) {
        const int cur = tk & 1;
        float4 nxt;
        if (tk < 63) nxt = ebg[(tk + 1) * 256 + tid];   // issue early (T14)

        const char* bb = &ebuf[cur][0];
        s16x8 ch0 = *(const s16x8*)(bb + lane * 16);
        s16x8 ch1 = *(const s16x8*)(bb + 1024 + lane * 16);
        s16x8 cl0 = *(const s16x8*)(bb + 2048 + lane * 16);
        s16x8 cl1 = *(const s16x8*)(bb + 3072 + lane * 16);
        float cck = ckls[tk * 16 + l15];

        #pragma unroll
        for (int rt = 0; rt < 2; ++rt) {
            f32x4 acc = {cck, cck, cck, cck};   // C-in = ||e||^2
            acc = __builtin_amdgcn_mfma_f32_16x16x32_bf16(aH[rt][0], ch0, acc, 0, 0, 0);
            acc = __builtin_amdgcn_mfma_f32_16x16x32_bf16(aH[rt][1], ch1, acc, 0, 0, 0);
            acc = __builtin_amdgcn_mfma_f32_16x16x32_bf16(aL[rt][0], ch0, acc, 0, 0, 0);
            acc = __builtin_amdgcn_mfma_f32_16x16x32_bf16(aL[rt][1], ch1, acc, 0, 0, 0);
            acc = __builtin_amdgcn_mfma_f32_16x16x32_bf16(aH[rt][0], cl0, acc, 0, 0, 0);
            acc = __builtin_amdgcn_mfma_f32_16x16x32_bf16(aH[rt][1], cl1, acc, 0, 0, 0);
            #pragma unroll
            for (int r = 0; r < 4; ++r) {
                float s = acc[r];               // = ck - 2*dot (hi/lo accurate)
                int sl = rt * 4 + r;
                bool cond = s < tb1[sl];
                tb2[sl] = __builtin_amdgcn_fmed3f(s, tb1[sl], tb2[sl]);
                tb1[sl] = fminf(tb1[sl], s);
                tix[sl] = cond ? kcur : tix[sl];
            }
        }
        kcur += 16;

        if (tk < 63) ((float4*)&ebuf[cur ^ 1][0])[tid] = nxt;  // write late
        __syncthreads();
    }

    // ---- merge top-2 across the 16 lanes of each g-group ----
    #pragma unroll
    for (int m = 1; m <= 8; m <<= 1) {
        #pragma unroll
        for (int sl = 0; sl < 8; ++sl) {
            float ob1 = __shfl_xor(tb1[sl], m);
            float ob2 = __shfl_xor(tb2[sl], m);
            int   oid = __shfl_xor(tix[sl], m);
            if (ob1 < tb1[sl] || (ob1 == tb1[sl] && oid < tix[sl])) {
                tb2[sl] = fminf(tb1[sl], ob2);
                tb1[sl] = ob1;
                tix[sl] = oid;
            } else {
                tb2[sl] = fminf(tb2[sl], ob1);
            }
        }
    }

    if (l15 == 0) {
        #pragma unroll
        for (int sl = 0; sl < 8; ++sl) {
            int rloc = wv * 32 + (sl >> 2) * 16 + g * 4 + (sl & 3);
            idxbuf[rloc] = tix[sl];
            if (tb2[sl] - tb1[sl] < MARGIN) {
                int slot = atomicAdd(count, 1);
                if (slot < list_cap) {
                    list[slot] = rowbase + rloc;
                    rowbest[slot] = ~0ull;      // init for refineB's atomicMin
                }
            }
        }
    }
    __syncthreads();

    // ---- fused gather: out[rowbase + r][:] = ET[idx[r]][:] ----
    const float4* ET4 = (const float4*)ET;
    float4* out4 = (float4*)(out + (size_t)rowbase * DIM);
    #pragma unroll
    for (int p = 0; p < 8; ++p) {
        int f = p * 256 + tid;           // 0..2047
        int r = f >> 4, dq = f & 15;
        out4[f] = ET4[idxbuf[r] * 16 + dq];
    }
}

// Exact numpy-f32-chain distance for flagged rows (semantics validated
// R2-R6). One wave per (row, 64-k chunk): lane = k, E read in ORIGINAL
// [d][k] layout -> coalesced 4B/lane, loads independent. Wave-reduce to
// packed (ordbits(dist)<<32)|k key, one atomicMin per wave.
__global__ __launch_bounds__(256)
void vq_refineB(const float* __restrict__ x, const float* __restrict__ E,
                const float* __restrict__ ckseq,
                const int* __restrict__ count, const int* __restrict__ list,
                unsigned long long* __restrict__ rowbest, int list_cap) {
    #pragma clang fp contract(off)
    int n = *count;
    if (n > list_cap) n = list_cap;
    int items = n * 16;
    int gw = (blockIdx.x * blockDim.x + threadIdx.x) >> 6;
    int lane = threadIdx.x & 63;
    int nw = (gridDim.x * blockDim.x) >> 6;
    for (int it = gw; it < items; it += nw) {
        int slot = it >> 4, chunk = it & 15;
        int row = list[slot];
        const f32x4* z4 = (const f32x4*)(x + (size_t)row * DIM);

        // ||z||^2: numpy pairwise_sum n=64 (8-acc unrolled), validated order
        float r8[8];
        {
            f32x4 a = z4[0], b = z4[1];
            r8[0] = a.x * a.x; r8[1] = a.y * a.y; r8[2] = a.z * a.z; r8[3] = a.w * a.w;
            r8[4] = b.x * b.x; r8[5] = b.y * b.y; r8[6] = b.z * b.z; r8[7] = b.w * b.w;
        }
        #pragma unroll
        for (int gi = 1; gi < 8; ++gi) {
            f32x4 a = z4[gi * 2], b = z4[gi * 2 + 1];
            r8[0] = r8[0] + a.x * a.x; r8[1] = r8[1] + a.y * a.y;
            r8[2] = r8[2] + a.z * a.z; r8[3] = r8[3] + a.w * a.w;
            r8[4] = r8[4] + b.x * b.x; r8[5] = r8[5] + b.y * b.y;
            r8[6] = r8[6] + b.z * b.z; r8[7] = r8[7] + b.w * b.w;
        }
        float A = ((r8[0] + r8[1]) + (r8[2] + r8[3]))
                + ((r8[4] + r8[5]) + (r8[6] + r8[7]));

        int k = chunk * 64 + lane;
        float s = 0.f;                    // sequential fmaf over d (BLAS emu)
        #pragma unroll
        for (int q = 0; q < 16; ++q) {
            f32x4 zv = z4[q];
            s = fmaf(zv.x, E[(4 * q + 0) * KCB + k], s);
            s = fmaf(zv.y, E[(4 * q + 1) * KCB + k], s);
            s = fmaf(zv.z, E[(4 * q + 2) * KCB + k], s);
            s = fmaf(zv.w, E[(4 * q + 3) * KCB + k], s);
        }
        float t = A + ckseq[k];
        float dist = t - 2.0f * s;

        // pack: monotone float ordbits in high 32, k in low 32
        unsigned u = __float_as_uint(dist);
        unsigned ord = u ^ ((u & 0x80000000u) ? 0xFFFFFFFFu : 0x80000000u);
        unsigned long long key = ((unsigned long long)ord << 32) | (unsigned)k;
        #pragma unroll
        for (int off = 32; off; off >>= 1) {
            unsigned long long ok = __shfl_xor(key, off);
            key = ok < key ? ok : key;
        }
        if (lane == 0) atomicMin(rowbest + slot, key);
    }
}

__global__ void vq_refineC(const float* __restrict__ ET,
                           float* __restrict__ out,
                           const int* __restrict__ count,
                           const int* __restrict__ list,
                           const unsigned long long* __restrict__ rowbest,
                           int list_cap) {
    int n = *count;
    if (n > list_cap) n = list_cap;
    int gw = (blockIdx.x * blockDim.x + threadIdx.x) >> 6;
    int lane = threadIdx.x & 63;
    int nw = (gridDim.x * blockDim.x) >> 6;
    for (int slot = gw; slot < n; slot += nw) {
        int row = list[slot];
        unsigned k = (unsigned)(rowbest[slot] & 0xFFFFFFFFu);
        out[(size_t)row * DIM + lane] = ET[(size_t)k * DIM + lane];
    }
}

extern "C" void kernel_launch(void* const* d_in, const int* in_sizes, int n_in,
                              void* d_out, int out_size, void* d_ws, size_t ws_size,
                              hipStream_t stream) {
    const float* x = (const float*)d_in[0];
    const float* E = (const float*)d_in[1];
    float* out = (float*)d_out;

    char* ws = (char*)d_ws;
    float* ET  = (float*)(ws + ET_OFF);
    float* ck  = (float*)(ws + CK_OFF);
    char*  EB  = ws + EB_OFF;
    int*   cnt = (int*)(ws + CNT_OFF);
    unsigned long long* rb = (unsigned long long*)(ws + RB_OFF);
    int*   lst = (int*)(ws + LIST_OFF);
    long long avail = (long long)ws_size - LIST_OFF;
    int list_cap = avail > 0 ? (int)(avail / 4) : 0;
    if (list_cap > RB_CAP) list_cap = RB_CAP;

    hipMemsetAsync(cnt, 0, sizeof(int), stream);
    vq_prep<<<4, 256, 0, stream>>>(E, ET, ck, EB);
    vq_mfma<<<NROWS / 128, 256, 0, stream>>>(x, ck, EB, ET, out, cnt, lst, rb, list_cap);
    vq_refineB<<<512, 256, 0, stream>>>(x, E, ck, cnt, lst, rb, list_cap);
    vq_refineC<<<128, 256, 0, stream>>>(ET, out, cnt, lst, rb, list_cap);
}